// Round 8
// baseline (157.016 us; speedup 1.0000x reference)
//
#include <hip/hip_runtime.h>
#include <stdint.h>

// Q2Linear int8 path, 2 dispatches. R8: weights staged as 2-BIT packed.
//   prep: blocks 0..1023    — per-row quantize x fp32 -> i8 (q = rowmax/127)
//         blocks 1024..1151 — pack w int32 {-2..1} -> 2-bit (w+2), layout
//                             [slab][n][chunk] so a block's per-slab B slice
//                             is 4 KB contiguous.
//   q8_gemm: i8 MFMA 16x16x64, tile 64m x 128n, BK=128, 512 blocks = 2/CU.
//            A staged via global_load_lds (verified path). B staged as ONE
//            coalesced dwordx4/thread of packed bits, unpacked in-register
//            (OR-spread + v_perm LUT) and ds_write_b128 into the verified
//            XOR-swizzled LDS layout. Global bytes/slab halve (L2-supply-bound
//            per R3/R6/R7 evidence) -> gemm should drop ~2x.

#define MM 1024
#define NN 4096
#define KK 4096
#define BK 128

typedef __attribute__((ext_vector_type(4))) int intx4;
typedef __attribute__((ext_vector_type(4))) float floatx4;

typedef const __attribute__((address_space(1))) void global_cvoid;
typedef __attribute__((address_space(3))) void lds_void;

// 16x 2-bit fields (value w+2 in 0..3) -> 16 signed i8 bytes
__device__ __forceinline__ intx4 unpack16(unsigned p) {
    intx4 o;
#pragma unroll
    for (int g = 0; g < 4; ++g) {
        unsigned t = (p >> (8 * g)) & 0xFFu;
        // spread 4x2b -> byte lanes (OR-based: no carries)
        unsigned s = (t | (t << 6) | (t << 12) | (t << 18)) & 0x03030303u;
        // LUT: field 0->0xFE(-2) 1->0xFF(-1) 2->0x00 3->0x01
        o[g] = (int)__builtin_amdgcn_perm(0u, 0x0100FFFEu, s);
    }
    return o;
}

// ---- prep: quantize x (blocks < MM) OR pack w to 2-bit (128 blocks) ----------
__global__ __launch_bounds__(256) void prep(const float* __restrict__ x,
                                            const int* __restrict__ wq,
                                            char* __restrict__ xq,
                                            float* __restrict__ qrow,
                                            unsigned* __restrict__ wp) {
    const int tid = threadIdx.x;
    if (blockIdx.x < MM) {
        const int m = blockIdx.x;
        const float* xr = x + (size_t)m * KK;
        floatx4 v[4];
        float amax = 0.f;
#pragma unroll
        for (int c = 0; c < 4; ++c) {
            v[c] = *(const floatx4*)(xr + (c * 256 + tid) * 4);
#pragma unroll
            for (int e = 0; e < 4; ++e) amax = fmaxf(amax, fabsf(v[c][e]));
        }
#pragma unroll
        for (int off = 32; off; off >>= 1) amax = fmaxf(amax, __shfl_down(amax, off));
        __shared__ float wmax[4];
        if ((tid & 63) == 0) wmax[tid >> 6] = amax;
        __syncthreads();
        amax = fmaxf(fmaxf(wmax[0], wmax[1]), fmaxf(wmax[2], wmax[3]));
        amax = fmaxf(amax, 1e-20f);
        const float qinv = 127.0f / amax;
        if (tid == 0) qrow[m] = amax / 127.0f;
#pragma unroll
        for (int c = 0; c < 4; ++c) {
            int p = 0;
#pragma unroll
            for (int e = 0; e < 4; ++e) {
                float r = rintf(v[c][e] * qinv);
                r = fminf(fmaxf(r, -127.f), 127.f);
                p |= ((int)r & 255) << (8 * e);
            }
            *(int*)(xq + (size_t)m * KK + (c * 256 + tid) * 4) = p;
        }
    } else {
        // pack w: block covers 32 rows; thread -> (row = tid>>3, chunk c = tid&7)
        const int blk = blockIdx.x - MM;          // 0..127
        const int n   = blk * 32 + (tid >> 3);
        const int c   = tid & 7;
        const int* wr = wq + (size_t)n * KK + c * 16;
        for (int slab = 0; slab < 32; ++slab) {
            const int* p4 = wr + slab * 128;
            unsigned pk = 0;
#pragma unroll
            for (int e = 0; e < 4; ++e) {
                intx4 a = *(const intx4*)(p4 + e * 4);
                unsigned b = (unsigned)(((a[0] + 2) & 3) | (((a[1] + 2) & 3) << 2) |
                                        (((a[2] + 2) & 3) << 4) | (((a[3] + 2) & 3) << 6));
                pk |= b << (8 * e);
            }
            wp[(size_t)slab * (NN * 8) + n * 8 + c] = pk;
        }
    }
}

// ---- GEMM: 64x128 tile, 4 waves (each 64m x 32n) -----------------------------
__global__ __launch_bounds__(256) void q8_gemm(const char* __restrict__ xq,
                                               const unsigned* __restrict__ wp,
                                               const float* __restrict__ qrow,
                                               const float* __restrict__ scales,
                                               float* __restrict__ out) {
    __shared__ char As[2][64 * BK];    // 8 KB each
    __shared__ char Bs[2][128 * BK];   // 16 KB each
    __shared__ float Sl[128 * 33];     // scales [n_local][block], +1 pad
    // total ~65 KB -> 2 blocks/CU

    const int tid  = threadIdx.x;
    const int lane = tid & 63;
    const int wave = tid >> 6;
    const int r16  = lane & 15;
    const int quad = lane >> 4;
    const int sw   = r16 & 7;
    const int wn   = wave * 32;

    // XCD pinning: bid&7 -> XCD; each XCD owns 4 n-tiles; xq (4MB) L2-resident/XCD
    const int bid = blockIdx.x;
    const int xcd = bid & 7, loc = bid >> 3;
    const int nT = xcd * 4 + (loc & 3);        // 0..31
    const int mT = loc >> 2;                   // 0..15
    const int mBase = mT * 64, nBase = nT * 128;

    // A staging address permute -> XOR-swizzled LDS tile (verified, 0 conflicts)
    const int rg = lane >> 3;
    const int cs = (lane & 7) ^ rg;
    const char* gA = xq + (size_t)(mBase + wave * 16 + rg) * KK + cs * 16;
    const int ldsRowA = wave * 16;

    // B packed: per-slab slice is 1024 dwords contiguous at slab*32768 + nBase*8
    const unsigned* gBp = wp + (size_t)nBase * 8 + (size_t)tid * 4;
    // unpack target: thread -> row n_l = tid>>1, chunks (tid&1)*4 + e
    const int n_l = tid >> 1;
    const int cb  = (tid & 1) * 4;

    floatx4 facc[4][2];
#pragma unroll
    for (int i = 0; i < 4; ++i)
#pragma unroll
        for (int j = 0; j < 2; ++j) facc[i][j] = (floatx4){0.f, 0.f, 0.f, 0.f};

#define STAGE_A(BUF, SLAB)                                                      \
    {                                                                           \
        _Pragma("unroll")                                                       \
        for (int t = 0; t < 2; ++t)                                             \
            __builtin_amdgcn_global_load_lds(                                   \
                (global_cvoid*)(gA + (size_t)(t * 8) * KK + (SLAB) * BK),       \
                (lds_void*)&As[BUF][(ldsRowA + t * 8) * BK], 16, 0, 0);         \
    }

#define LOADB(DST, SLAB) DST = *(const intx4*)(gBp + (size_t)(SLAB) * (NN * 8));

#define UNPACKB(BUF, BP)                                                        \
    {                                                                           \
        char* ubase = &Bs[BUF][n_l * 128];                                      \
        _Pragma("unroll")                                                       \
        for (int e = 0; e < 4; ++e)                                             \
            *(intx4*)(ubase + (((cb + e) ^ (n_l & 7)) * 16)) =                  \
                unpack16((unsigned)BP[e]);                                      \
    }

#define COMPUTE(BUF, SLAB)                                                      \
    {                                                                           \
        float sf0 = Sl[(wn + r16) * 33 + (SLAB)];                               \
        float sf1 = Sl[(wn + 16 + r16) * 33 + (SLAB)];                          \
        intx4 iacc[4][2];                                                       \
        _Pragma("unroll")                                                       \
        for (int kp = 0; kp < 2; ++kp) {                                        \
            intx4 av[4], bv[2];                                                 \
            _Pragma("unroll")                                                   \
            for (int i = 0; i < 4; ++i)                                         \
                av[i] = *(const intx4*)&As[BUF][(i * 16 + r16) * BK +           \
                                               (((kp * 4 + quad) ^ sw) << 4)];  \
            _Pragma("unroll")                                                   \
            for (int j = 0; j < 2; ++j)                                         \
                bv[j] = *(const intx4*)&Bs[BUF][(wn + j * 16 + r16) * BK +      \
                                               (((kp * 4 + quad) ^ sw) << 4)];  \
            _Pragma("unroll")                                                   \
            for (int i = 0; i < 4; ++i)                                         \
                _Pragma("unroll")                                               \
                for (int j = 0; j < 2; ++j)                                     \
                    iacc[i][j] = __builtin_amdgcn_mfma_i32_16x16x64_i8(         \
                        av[i], bv[j], kp ? iacc[i][j] : (intx4){0, 0, 0, 0},    \
                        0, 0, 0);                                               \
        }                                                                       \
        _Pragma("unroll")                                                       \
        for (int i = 0; i < 4; ++i)                                             \
            _Pragma("unroll")                                                   \
            for (int r = 0; r < 4; ++r) {                                       \
                facc[i][0][r] += (float)iacc[i][0][r] * sf0;                    \
                facc[i][1][r] += (float)iacc[i][1][r] * sf1;                    \
            }                                                                   \
    }

    // prologue: stage slab 0 (A direct, B load+unpack), scales
    STAGE_A(0, 0)
    intx4 bp0;
    LOADB(bp0, 0)
    for (int t = tid; t < 4096; t += 256) {
        int nl = t >> 5, b = t & 31;
        Sl[nl * 33 + b] = scales[(size_t)(nBase + nl) * 32 + b];
    }
    UNPACKB(0, bp0)
    __syncthreads();

    const int NIT = KK / BK;  // 32
    for (int it = 0; it < NIT; it += 2) {
        intx4 bp1;
        LOADB(bp1, it + 1)                      // in flight across COMPUTE
        if (it + 1 < NIT) STAGE_A(1, it + 1)
        COMPUTE(0, it)
        UNPACKB(1, bp1)
        __syncthreads();
        intx4 bp2;
        LOADB(bp2, (it + 2) & 31)               // last iter: harmless dup
        if (it + 2 < NIT) STAGE_A(0, it + 2)
        COMPUTE(1, it + 1)
        UNPACKB(0, bp2)
        __syncthreads();
    }

    // epilogue: C/D col = lane&15 (n), row = quad*4 + reg (m); fold q[m]
#pragma unroll
    for (int i = 0; i < 4; ++i) {
        floatx4 qv = *(const floatx4*)(qrow + mBase + i * 16 + quad * 4);
#pragma unroll
        for (int r = 0; r < 4; ++r) {
            int mg = mBase + i * 16 + quad * 4 + r;
            float* orow = out + (size_t)mg * NN + nBase + wn + r16;
#pragma unroll
            for (int j = 0; j < 2; ++j) orow[j * 16] = facc[i][j][r] * qv[r];
        }
    }
#undef STAGE_A
#undef LOADB
#undef UNPACKB
#undef COMPUTE
}

extern "C" void kernel_launch(void* const* d_in, const int* in_sizes, int n_in,
                              void* d_out, int out_size, void* d_ws, size_t ws_size,
                              hipStream_t stream) {
    const float* x      = (const float*)d_in[0];
    const int*   wq     = (const int*)d_in[1];
    const float* scales = (const float*)d_in[2];
    float*       out    = (float*)d_out;

    char*     xq   = (char*)d_ws;                                   // 4 MB
    float*    qrow = (float*)((char*)d_ws + (size_t)MM * KK);       // 4 KB
    unsigned* wp   = (unsigned*)((char*)d_ws + (size_t)MM * KK + 4096);  // 4 MB

    prep<<<MM + NN / 32, 256, 0, stream>>>(x, wq, xq, qrow, wp);
    q8_gemm<<<(MM / 64) * (NN / 128), 256, 0, stream>>>(xq, wp, qrow, scales, out);
}